// Round 1
// baseline (633.510 us; speedup 1.0000x reference)
//
#include <hip/hip_runtime.h>
#include <math.h>

#define G_ 4
#define N_ 4096
#define E_ 65536
#define NB_ 8
#define C_ 32
#define NZ_ 3
#define RC_ 6.0f

// ---------- helpers ----------
__device__ __forceinline__ float red32(float v) {
    // reduce across 32-lane channel group (half-wave)
    #pragma unroll
    for (int o = 16; o >= 1; o >>= 1) v += __shfl_xor(v, o, 32);
    return v;
}

// ---------- h0 = node_attr @ Wz ----------
__global__ void k_h0(const float* __restrict__ na, const float* __restrict__ Wz,
                     float* __restrict__ h) {
    int idx = blockIdx.x * 256 + threadIdx.x;      // over G*N*C
    int c  = idx & (C_ - 1);
    int gn = idx >> 5;                              // g*N + n
    const float* a = na + (size_t)gn * NZ_;
    float v = a[0] * Wz[0 * C_ + c] + a[1] * Wz[1 * C_ + c] + a[2] * Wz[2 * C_ + c];
    h[idx] = v;
}

// ---------- message pass: thread = (edge, channel); atomics into A[G,N,9,C] ----------
__global__ void k_edge(const float* __restrict__ x, const float* __restrict__ xv,
                       const int* __restrict__ ei, const float* __restrict__ Wrad,
                       const float* __restrict__ h, float* __restrict__ A) {
    __shared__ float sW[NB_ * C_ * 3];
    for (int i = threadIdx.x; i < NB_ * C_ * 3; i += 256) sW[i] = Wrad[i];
    __syncthreads();

    int idx = blockIdx.x * 256 + threadIdx.x;      // over G*E*C
    int c  = idx & 31;
    int eg = idx >> 5;                              // g*E + e
    int g  = eg >> 16;                              // E = 65536
    int e  = eg & 65535;

    float r  = x[eg];
    float vx = xv[eg * 3 + 0], vy = xv[eg * 3 + 1], vz = xv[eg * 3 + 2];
    const int* eib = ei + (size_t)g * 2 * E_;
    int src = eib[e];
    int dst = eib[E_ + e];

    // Bessel basis: sqrt(2/RC) * sin(n*pi*r/RC)/r  (sinc-safe at r=0)
    const float SQ2RC = 0.57735026918962576f;       // sqrt(2/6)
    float R[NB_];
    float rinv = (r > 1e-12f) ? (1.0f / r) : 0.0f;
    #pragma unroll
    for (int n = 1; n <= NB_; ++n) {
        float k = ((float)M_PI * (float)n) / RC_;
        R[n - 1] = (r > 1e-12f) ? (SQ2RC * sinf(k * r) * rinv) : (SQ2RC * k);
    }

    // spherical harmonics of unit edge vector
    float nrm = sqrtf(vx * vx + vy * vy + vz * vz) + 1e-9f;
    float ux = vx / nrm, uy = vy / nrm, uz = vz / nrm;
    const float SQ3  = 1.7320508075688772f;
    const float CY2  = 2.7386127875258306f;         // sqrt(15/2)
    const float CY2S = CY2 * 1.4142135623730951f;   // CY2*sqrt(2)
    const float IS6  = 0.4082482904638631f;         // 1/sqrt(6)
    const float IS2  = 0.7071067811865476f;         // 1/sqrt(2)
    float Y1x = SQ3 * ux, Y1y = SQ3 * uy, Y1z = SQ3 * uz;
    float Y20 = CY2S * ux * uy;
    float Y21 = CY2S * uy * uz;
    float Y22 = CY2 * (2.0f * uz * uz - ux * ux - uy * uy) * IS6;
    float Y23 = CY2S * ux * uz;
    float Y24 = CY2 * (ux * ux - uy * uy) * IS2;

    // w[c][l] = sum_n R[n] * Wrad[n][c][l]
    float w0 = 0.f, w1 = 0.f, w2 = 0.f;
    #pragma unroll
    for (int n = 0; n < NB_; ++n) {
        const float* Wn = sW + n * C_ * 3 + c * 3;
        w0 += R[n] * Wn[0];
        w1 += R[n] * Wn[1];
        w2 += R[n] * Wn[2];
    }

    float hs = h[((size_t)g * N_ + src) * C_ + c];
    float m0 = w0 * hs, m1 = w1 * hs, m2 = w2 * hs;

    float* Ab = A + (((size_t)g * N_ + dst) * 9) * C_ + c;
    atomicAdd(Ab + 0 * C_, m0);
    atomicAdd(Ab + 1 * C_, m1 * Y1x);
    atomicAdd(Ab + 2 * C_, m1 * Y1y);
    atomicAdd(Ab + 3 * C_, m1 * Y1z);
    atomicAdd(Ab + 4 * C_, m2 * Y20);
    atomicAdd(Ab + 5 * C_, m2 * Y21);
    atomicAdd(Ab + 6 * C_, m2 * Y22);
    atomicAdd(Ab + 7 * C_, m2 * Y23);
    atomicAdd(Ab + 8 * C_, m2 * Y24);
}

// ---------- node stage: prod3body (B0,B2 only) + readout accum (+ f0 on pass 1) ----------
template <int PASS>
__global__ void k_node(const float* __restrict__ A, const float* __restrict__ Wp,
                       const float* __restrict__ Wr0, const float* __restrict__ Wr2,
                       const float* __restrict__ Wm0, float* __restrict__ f0out,
                       float* __restrict__ acc) {
    __shared__ float sB0[8][C_];
    __shared__ float sred[8][6];
    int tid = threadIdx.x;
    int grp = tid >> 5;
    int c   = tid & 31;
    int gn  = blockIdx.x * 8 + grp;                 // g*N + n
    int g   = gn >> 12;                             // N = 4096

    const float* Ab = A + (size_t)gn * 9 * C_ + c;
    float a0  = Ab[0 * C_];
    float a1x = Ab[1 * C_], a1y = Ab[2 * C_], a1z = Ab[3 * C_];
    float a20 = Ab[4 * C_], a21 = Ab[5 * C_], a22 = Ab[6 * C_],
          a23 = Ab[7 * C_], a24 = Ab[8 * C_];

    float d11 = a1x * a1x + a1y * a1y + a1z * a1z;
    float d22 = a20 * a20 + a21 * a21 + a22 * a22 + a23 * a23 + a24 * a24;

    float B0 = Wp[0 * C_ + c] * a0 * a0 + Wp[1 * C_ + c] * d11 + Wp[2 * C_ + c] * d22;

    float w5 = Wp[5 * C_ + c], w6 = Wp[6 * C_ + c];
    const float S2  = 1.4142135623730951f;
    const float IS6 = 0.4082482904638631f;
    const float IS2 = 0.7071067811865476f;
    float B20 = w5 * a0 * a20 + w6 * (S2 * a1x * a1y);
    float B21 = w5 * a0 * a21 + w6 * (S2 * a1y * a1z);
    float B22 = w5 * a0 * a22 + w6 * ((2.0f * a1z * a1z - a1x * a1x - a1y * a1y) * IS6);
    float B23 = w5 * a0 * a23 + w6 * (S2 * a1x * a1z);
    float B24 = w5 * a0 * a24 + w6 * ((a1x * a1x - a1y * a1y) * IS2);

    float wr0 = Wr0[c], wr2 = Wr2[c];
    float rs  = red32(B0 * wr0);
    float rt0 = red32(B20 * wr2);
    float rt1 = red32(B21 * wr2);
    float rt2 = red32(B22 * wr2);
    float rt3 = red32(B23 * wr2);
    float rt4 = red32(B24 * wr2);
    if (c == 0) {
        sred[grp][0] = rs;
        sred[grp][1] = rt0; sred[grp][2] = rt1; sred[grp][3] = rt2;
        sred[grp][4] = rt3; sred[grp][5] = rt4;
    }
    if (PASS == 1) sB0[grp][c] = B0;
    __syncthreads();

    if (tid < 6) {
        float s = 0.f;
        #pragma unroll
        for (int k = 0; k < 8; ++k) s += sred[k][tid];
        atomicAdd(&acc[g * 6 + tid], s);
    }

    if (PASS == 1) {
        // f0 = silu(B0 @ Wm0), needs all channels of this node's B0
        float s = 0.f;
        #pragma unroll
        for (int k = 0; k < C_; ++k) s += sB0[grp][k] * Wm0[k * C_ + c];
        float sig = 1.0f / (1.0f + expf(-s));
        f0out[(size_t)gn * C_ + c] = s * sig;
    }
}

// ---------- finalize: out[g] = (s)/sqrt3 * I + mat_from_t5(t) ----------
__global__ void k_final(const float* __restrict__ acc, float* __restrict__ out) {
    int g = threadIdx.x;
    if (g >= G_) return;
    float s  = acc[g * 6 + 0];
    float ta = acc[g * 6 + 1], tb = acc[g * 6 + 2], tc = acc[g * 6 + 3],
          td = acc[g * 6 + 4], te = acc[g * 6 + 5];
    const float IS3 = 0.5773502691896258f;
    const float IS6 = 0.4082482904638631f;
    const float IS2 = 0.7071067811865476f;
    float diag = s * IS3;
    float Sxx = -tc * IS6 + te * IS2 + diag;
    float Syy = -tc * IS6 - te * IS2 + diag;
    float Szz = 2.0f * tc * IS6 + diag;
    float Sxy = ta * IS2, Syz = tb * IS2, Sxz = td * IS2;
    float* o = out + g * 9;
    o[0] = Sxx; o[1] = Sxy; o[2] = Sxz;
    o[3] = Sxy; o[4] = Syy; o[5] = Syz;
    o[6] = Sxz; o[7] = Syz; o[8] = Szz;
}

extern "C" void kernel_launch(void* const* d_in, const int* in_sizes, int n_in,
                              void* d_out, int out_size, void* d_ws, size_t ws_size,
                              hipStream_t stream) {
    const float* x     = (const float*)d_in[0];
    const float* xv    = (const float*)d_in[1];
    const float* na    = (const float*)d_in[2];
    const int*   ei    = (const int*)d_in[3];
    const float* Wz    = (const float*)d_in[4];
    const float* Wrad1 = (const float*)d_in[5];
    const float* Wrad2 = (const float*)d_in[6];
    const float* Wp    = (const float*)d_in[7];
    const float* Wr0_1 = (const float*)d_in[8];
    const float* Wr2_1 = (const float*)d_in[9];
    const float* Wm0   = (const float*)d_in[10];
    const float* Wr0_2 = (const float*)d_in[11];
    const float* Wr2_2 = (const float*)d_in[12];
    float* out = (float*)d_out;

    float* ws  = (float*)d_ws;
    const size_t A_elems = (size_t)G_ * N_ * 9 * C_;   // 4,718,592
    const size_t H_elems = (size_t)G_ * N_ * C_;       //   524,288
    float* A   = ws;
    float* h   = ws + A_elems;
    float* acc = h + H_elems;

    hipMemsetAsync(acc, 0, 6 * G_ * sizeof(float), stream);
    k_h0<<<(G_ * N_ * C_) / 256, 256, 0, stream>>>(na, Wz, h);

    // ---- pass 1 ----
    hipMemsetAsync(A, 0, A_elems * sizeof(float), stream);
    k_edge<<<((size_t)G_ * E_ * C_) / 256, 256, 0, stream>>>(x, xv, ei, Wrad1, h, A);
    k_node<1><<<(G_ * N_) / 8, 256, 0, stream>>>(A, Wp, Wr0_1, Wr2_1, Wm0, h, acc);

    // ---- pass 2 (h now holds f0) ----
    hipMemsetAsync(A, 0, A_elems * sizeof(float), stream);
    k_edge<<<((size_t)G_ * E_ * C_) / 256, 256, 0, stream>>>(x, xv, ei, Wrad2, h, A);
    k_node<2><<<(G_ * N_) / 8, 256, 0, stream>>>(A, Wp, Wr0_2, Wr2_2, nullptr, nullptr, acc);

    k_final<<<1, 64, 0, stream>>>(acc, out);
}

// Round 2
// 247.490 us; speedup vs baseline: 2.5597x; 2.5597x over previous
//
#include <hip/hip_runtime.h>
#include <math.h>

#define G_ 4
#define N_ 4096
#define E_ 65536
#define NB_ 8
#define C_ 32

// ---------- helpers ----------
__device__ __forceinline__ float red32(float v) {
    #pragma unroll
    for (int o = 16; o >= 1; o >>= 1) v += __shfl_xor(v, o, 32);
    return v;
}

// ---------- h0 = node_attr @ Wz ----------
__global__ void k_h0(const float* __restrict__ na, const float* __restrict__ Wz,
                     float* __restrict__ h) {
    int idx = blockIdx.x * 256 + threadIdx.x;      // over G*N*C
    int c  = idx & (C_ - 1);
    int gn = idx >> 5;
    const float* a = na + (size_t)gn * 3;
    h[idx] = a[0] * Wz[0 * C_ + c] + a[1] * Wz[1 * C_ + c] + a[2] * Wz[2 * C_ + c];
}

// ---------- degree histogram ----------
__global__ void k_hist(const int* __restrict__ ei, int* __restrict__ deg) {
    int idx = blockIdx.x * 256 + threadIdx.x;      // g*E + e
    int g = idx >> 16, e = idx & (E_ - 1);
    int dst = ei[(size_t)g * 2 * E_ + E_ + e];
    atomicAdd(&deg[g * N_ + dst], 1);
}

// ---------- exclusive scan over 4096 degrees per graph (1 block/graph) ----------
__global__ void k_scan(const int* __restrict__ deg, int* __restrict__ row) {
    __shared__ int sums[1024];
    int g = blockIdx.x;
    int t = threadIdx.x;
    const int* d = deg + g * N_;
    int v0 = d[4 * t], v1 = d[4 * t + 1], v2 = d[4 * t + 2], v3 = d[4 * t + 3];
    int s = v0 + v1 + v2 + v3;
    sums[t] = s;
    __syncthreads();
    for (int off = 1; off < 1024; off <<= 1) {
        int x = (t >= off) ? sums[t - off] : 0;
        __syncthreads();
        sums[t] += x;
        __syncthreads();
    }
    int base = (t > 0) ? sums[t - 1] : 0;
    int* r = row + g * (N_ + 1);
    r[4 * t]     = base;
    r[4 * t + 1] = base + v0;
    r[4 * t + 2] = base + v0 + v1;
    r[4 * t + 3] = base + v0 + v1 + v2;
    if (t == 0) r[N_] = E_;
}

// ---------- per-edge prep: slot assign + Bessel + record scatter ----------
__global__ void k_prep(const float* __restrict__ x, const float* __restrict__ xv,
                       const int* __restrict__ ei, const int* __restrict__ row,
                       int* __restrict__ cursor, float* __restrict__ Rbuf,
                       float4* __restrict__ rec) {
    int idx = blockIdx.x * 256 + threadIdx.x;      // g*E + e
    int g = idx >> 16, e = idx & (E_ - 1);
    const int* eib = ei + (size_t)g * 2 * E_;
    int src = eib[e], dst = eib[E_ + e];
    int local = atomicAdd(&cursor[g * N_ + dst], 1);
    int slot = g * E_ + row[g * (N_ + 1) + dst] + local;

    float r = x[idx];
    const float SQ2RC = 0.57735026918962576f;       // sqrt(2/6)
    float rinv = (r > 1e-12f) ? (1.0f / r) : 0.0f;
    float R[NB_];
    #pragma unroll
    for (int n = 1; n <= NB_; ++n) {
        float k = 0.5235987755982988f * (float)n;   // n*pi/6
        R[n - 1] = (r > 1e-12f) ? (SQ2RC * __sinf(k * r) * rinv) : (SQ2RC * k);
    }
    float4* Rb = (float4*)(Rbuf + (size_t)slot * NB_);
    Rb[0] = make_float4(R[0], R[1], R[2], R[3]);
    Rb[1] = make_float4(R[4], R[5], R[6], R[7]);

    float4 rc;
    rc.x = xv[(size_t)idx * 3 + 0];
    rc.y = xv[(size_t)idx * 3 + 1];
    rc.z = xv[(size_t)idx * 3 + 2];
    rc.w = __int_as_float(src);
    rec[slot] = rc;
}

// ---------- fused gather + prod3body + readout (+ f0 on pass 1) ----------
// one wave per node: 64 lanes = 32 channels x 2 edges/iteration
template <int PASS>
__global__ void __launch_bounds__(256) k_node(
        const float* __restrict__ Rbuf, const float4* __restrict__ rec,
        const int* __restrict__ row, const float* __restrict__ hin,
        const float* __restrict__ Wrad, const float* __restrict__ Wp,
        const float* __restrict__ Wr0, const float* __restrict__ Wr2,
        const float* __restrict__ Wm0, float* __restrict__ f0out,
        float* __restrict__ acc) {
    __shared__ float sred[4][6];
    int tid  = threadIdx.x;
    int wv   = tid >> 6;
    int lane = tid & 63;
    int c    = lane & 31;
    int eo   = lane >> 5;
    int gn   = blockIdx.x * 4 + wv;                 // g*N + n (4096%4==0: no straddle)
    int g    = gn >> 12;
    int n    = gn & (N_ - 1);

    // per-lane Wrad column: wc[nb][l] = Wrad[nb][c][l]
    float wc[NB_][3];
    #pragma unroll
    for (int nb = 0; nb < NB_; ++nb)
        #pragma unroll
        for (int l = 0; l < 3; ++l)
            wc[nb][l] = Wrad[nb * (C_ * 3) + c * 3 + l];

    const int* rp = row + g * (N_ + 1);
    int start = rp[n], end = rp[n + 1];

    const float SQ3  = 1.7320508075688772f;   // Y1 scale
    const float S15  = 3.8729833462074170f;   // sqrt(15)
    const float C22  = 1.1180339887498949f;   // sqrt(5)/2
    const float C24  = 1.9364916731037085f;   // sqrt(15)/2

    float A0 = 0, A1x = 0, A1y = 0, A1z = 0;
    float A20 = 0, A21 = 0, A22 = 0, A23 = 0, A24 = 0;

    for (int s = start + eo; s < end; s += 2) {
        size_t slot = (size_t)g * E_ + s;
        float4 rc = rec[slot];
        const float4* Rb = (const float4*)(Rbuf + slot * NB_);
        float4 Ra = Rb[0], Rc = Rb[1];
        int src = __float_as_int(rc.w);
        float hs = hin[((size_t)g * N_ + src) * C_ + c];

        float nrm = sqrtf(rc.x * rc.x + rc.y * rc.y + rc.z * rc.z) + 1e-9f;
        float inr = 1.0f / nrm;
        float ux = rc.x * inr, uy = rc.y * inr, uz = rc.z * inr;

        float Rv[NB_] = {Ra.x, Ra.y, Ra.z, Ra.w, Rc.x, Rc.y, Rc.z, Rc.w};
        float w0 = 0.f, w1 = 0.f, w2 = 0.f;
        #pragma unroll
        for (int nb = 0; nb < NB_; ++nb) {
            w0 += Rv[nb] * wc[nb][0];
            w1 += Rv[nb] * wc[nb][1];
            w2 += Rv[nb] * wc[nb][2];
        }
        float m0 = w0 * hs, m1 = w1 * hs, m2 = w2 * hs;

        A0  += m0;
        A1x += m1 * (SQ3 * ux);
        A1y += m1 * (SQ3 * uy);
        A1z += m1 * (SQ3 * uz);
        A20 += m2 * (S15 * ux * uy);
        A21 += m2 * (S15 * uy * uz);
        A22 += m2 * (C22 * (2.0f * uz * uz - ux * ux - uy * uy));
        A23 += m2 * (S15 * ux * uz);
        A24 += m2 * (C24 * (ux * ux - uy * uy));
    }

    // fold the two edge-halves (both halves end with the full sum)
    A0  += __shfl_xor(A0, 32);
    A1x += __shfl_xor(A1x, 32);
    A1y += __shfl_xor(A1y, 32);
    A1z += __shfl_xor(A1z, 32);
    A20 += __shfl_xor(A20, 32);
    A21 += __shfl_xor(A21, 32);
    A22 += __shfl_xor(A22, 32);
    A23 += __shfl_xor(A23, 32);
    A24 += __shfl_xor(A24, 32);

    // prod3body: B0 and B2 paths only (B1 is dead code w.r.t. outputs)
    float d11 = A1x * A1x + A1y * A1y + A1z * A1z;
    float d22 = A20 * A20 + A21 * A21 + A22 * A22 + A23 * A23 + A24 * A24;
    float B0 = Wp[0 * C_ + c] * A0 * A0 + Wp[1 * C_ + c] * d11 + Wp[2 * C_ + c] * d22;

    float w5 = Wp[5 * C_ + c], w6 = Wp[6 * C_ + c];
    const float S2  = 1.4142135623730951f;
    const float IS6 = 0.4082482904638631f;
    const float IS2 = 0.7071067811865476f;
    float B20 = w5 * A0 * A20 + w6 * (S2 * A1x * A1y);
    float B21 = w5 * A0 * A21 + w6 * (S2 * A1y * A1z);
    float B22 = w5 * A0 * A22 + w6 * ((2.0f * A1z * A1z - A1x * A1x - A1y * A1y) * IS6);
    float B23 = w5 * A0 * A23 + w6 * (S2 * A1x * A1z);
    float B24 = w5 * A0 * A24 + w6 * ((A1x * A1x - A1y * A1y) * IS2);

    float wr0 = Wr0[c], wr2 = Wr2[c];
    float rs  = red32(B0 * wr0);
    float rt0 = red32(B20 * wr2);
    float rt1 = red32(B21 * wr2);
    float rt2 = red32(B22 * wr2);
    float rt3 = red32(B23 * wr2);
    float rt4 = red32(B24 * wr2);
    if (lane == 0) {
        sred[wv][0] = rs;
        sred[wv][1] = rt0; sred[wv][2] = rt1; sred[wv][3] = rt2;
        sred[wv][4] = rt3; sred[wv][5] = rt4;
    }

    if (PASS == 1) {
        // f0 = silu(B0 @ Wm0); B0 is node-local, broadcast via shuffles
        float s = 0.f;
        #pragma unroll
        for (int k = 0; k < C_; ++k) s += __shfl(B0, k, 32) * Wm0[k * C_ + c];
        float sig = 1.0f / (1.0f + __expf(-s));
        if (eo == 0) f0out[(size_t)gn * C_ + c] = s * sig;
    }

    __syncthreads();
    if (tid < 6) {
        float s = sred[0][tid] + sred[1][tid] + sred[2][tid] + sred[3][tid];
        atomicAdd(&acc[g * 6 + tid], s);
    }
}

// ---------- finalize ----------
__global__ void k_final(const float* __restrict__ acc, float* __restrict__ out) {
    int g = threadIdx.x;
    if (g >= G_) return;
    float s  = acc[g * 6 + 0];
    float ta = acc[g * 6 + 1], tb = acc[g * 6 + 2], tc = acc[g * 6 + 3],
          td = acc[g * 6 + 4], te = acc[g * 6 + 5];
    const float IS3 = 0.5773502691896258f;
    const float IS6 = 0.4082482904638631f;
    const float IS2 = 0.7071067811865476f;
    float diag = s * IS3;
    float Sxx = -tc * IS6 + te * IS2 + diag;
    float Syy = -tc * IS6 - te * IS2 + diag;
    float Szz = 2.0f * tc * IS6 + diag;
    float Sxy = ta * IS2, Syz = tb * IS2, Sxz = td * IS2;
    float* o = out + g * 9;
    o[0] = Sxx; o[1] = Sxy; o[2] = Sxz;
    o[3] = Sxy; o[4] = Syy; o[5] = Syz;
    o[6] = Sxz; o[7] = Syz; o[8] = Szz;
}

extern "C" void kernel_launch(void* const* d_in, const int* in_sizes, int n_in,
                              void* d_out, int out_size, void* d_ws, size_t ws_size,
                              hipStream_t stream) {
    const float* x     = (const float*)d_in[0];
    const float* xv    = (const float*)d_in[1];
    const float* na    = (const float*)d_in[2];
    const int*   ei    = (const int*)d_in[3];
    const float* Wz    = (const float*)d_in[4];
    const float* Wrad1 = (const float*)d_in[5];
    const float* Wrad2 = (const float*)d_in[6];
    const float* Wp    = (const float*)d_in[7];
    const float* Wr0_1 = (const float*)d_in[8];
    const float* Wr2_1 = (const float*)d_in[9];
    const float* Wm0   = (const float*)d_in[10];
    const float* Wr0_2 = (const float*)d_in[11];
    const float* Wr2_2 = (const float*)d_in[12];
    float* out = (float*)d_out;

    // ---- workspace layout (floats) ----
    float* ws = (float*)d_ws;
    const size_t R_FL   = (size_t)G_ * E_ * NB_;       // 2,097,152 (8 MiB)
    const size_t REC_FL = (size_t)G_ * E_ * 4;         // 1,048,576 (4 MiB)
    const size_t H_FL   = (size_t)G_ * N_ * C_;        //   524,288 (2 MiB)
    float*  Rbuf = ws;
    float4* rec  = (float4*)(ws + R_FL);
    float*  h    = ws + R_FL + REC_FL;
    float*  f0   = h + H_FL;
    int*    row  = (int*)(f0 + H_FL);                  // G*(N+1) = 16,388
    int*    deg  = row + 16392;                        // G*N
    int*    cur  = deg + G_ * N_;                      // G*N
    float*  acc  = (float*)(cur + G_ * N_);            // 24

    // zero: deg + cur + acc (contiguous)
    hipMemsetAsync(deg, 0, (2 * G_ * N_) * sizeof(int) + 24 * sizeof(float), stream);

    k_h0  <<<(G_ * N_ * C_) / 256, 256, 0, stream>>>(na, Wz, h);
    k_hist<<<(G_ * E_) / 256, 256, 0, stream>>>(ei, deg);
    k_scan<<<G_, 1024, 0, stream>>>(deg, row);
    k_prep<<<(G_ * E_) / 256, 256, 0, stream>>>(x, xv, ei, row, cur, Rbuf, rec);

    k_node<1><<<(G_ * N_) / 4, 256, 0, stream>>>(Rbuf, rec, row, h,  Wrad1, Wp,
                                                 Wr0_1, Wr2_1, Wm0, f0, acc);
    k_node<2><<<(G_ * N_) / 4, 256, 0, stream>>>(Rbuf, rec, row, f0, Wrad2, Wp,
                                                 Wr0_2, Wr2_2, nullptr, nullptr, acc);

    k_final<<<1, 64, 0, stream>>>(acc, out);
}

// Round 3
// 241.626 us; speedup vs baseline: 2.6219x; 1.0243x over previous
//
#include <hip/hip_runtime.h>
#include <math.h>

#define G_ 4
#define N_ 4096
#define E_ 65536
#define NB_ 8
#define C_ 32

// ---------- helpers ----------
__device__ __forceinline__ float red32(float v) {
    #pragma unroll
    for (int o = 16; o >= 1; o >>= 1) v += __shfl_xor(v, o, 32);
    return v;
}

// ---------- fused: h0 = node_attr @ Wz  +  degree histogram ----------
__global__ void k_h0_hist(const float* __restrict__ na, const float* __restrict__ Wz,
                          float* __restrict__ h, const int* __restrict__ ei,
                          int* __restrict__ deg) {
    int idx = blockIdx.x * 256 + threadIdx.x;      // over G*N*C = 524288
    int c  = idx & (C_ - 1);
    int gn = idx >> 5;
    const float* a = na + (size_t)gn * 3;
    h[idx] = a[0] * Wz[0 * C_ + c] + a[1] * Wz[1 * C_ + c] + a[2] * Wz[2 * C_ + c];

    if (idx < G_ * E_) {                            // first half also histograms
        int g = idx >> 16, e = idx & (E_ - 1);
        int dst = ei[(size_t)g * 2 * E_ + E_ + e];
        atomicAdd(&deg[g * N_ + dst], 1);
    }
}

// ---------- exclusive scan of 4096 degrees per graph (1 block/graph, shfl) ----------
__global__ void k_scan(const int* __restrict__ deg, int* __restrict__ row) {
    __shared__ int wsum[16];
    int g = blockIdx.x, t = threadIdx.x;
    int4 v = ((const int4*)(deg + g * N_))[t];      // 1024 threads x 4
    int s = v.x + v.y + v.z + v.w;
    int incl = s;
    int lane = t & 63, wv = t >> 6;
    #pragma unroll
    for (int off = 1; off < 64; off <<= 1) {
        int x = __shfl_up(incl, off, 64);
        if (lane >= off) incl += x;
    }
    if (lane == 63) wsum[wv] = incl;
    __syncthreads();
    if (t < 16) {
        int ws = wsum[t];
        int wincl = ws;
        #pragma unroll
        for (int off = 1; off < 16; off <<= 1) {
            int x = __shfl_up(wincl, off, 16);
            if (t >= off) wincl += x;
        }
        wsum[t] = wincl - ws;                       // exclusive wave offset
    }
    __syncthreads();
    int base = wsum[wv] + incl - s;
    int* r = row + g * (N_ + 1);
    r[4 * t]     = base;
    r[4 * t + 1] = base + v.x;
    r[4 * t + 2] = base + v.x + v.y;
    r[4 * t + 3] = base + v.x + v.y + v.z;
    if (t == 0) r[N_] = E_;
}

// ---------- per-edge prep: slot assign + Bessel + v=sqrt(3)*unit(vec) ----------
__global__ void k_prep(const float* __restrict__ x, const float* __restrict__ xv,
                       const int* __restrict__ ei, const int* __restrict__ row,
                       int* __restrict__ cursor, float* __restrict__ Rbuf,
                       float4* __restrict__ rec, int* __restrict__ srcb) {
    int idx = blockIdx.x * 256 + threadIdx.x;      // g*E + e
    int g = idx >> 16, e = idx & (E_ - 1);
    const int* eib = ei + (size_t)g * 2 * E_;
    int src = eib[e], dst = eib[E_ + e];
    int local = atomicAdd(&cursor[g * N_ + dst], 1);
    int slot = g * E_ + row[g * (N_ + 1) + dst] + local;

    float r = x[idx];
    const float SQ2RC = 0.57735026918962576f;       // sqrt(2/6)
    float rinv = (r > 1e-12f) ? (1.0f / r) : 0.0f;
    float R[NB_];
    #pragma unroll
    for (int n = 1; n <= NB_; ++n) {
        float k = 0.5235987755982988f * (float)n;   // n*pi/6
        R[n - 1] = (r > 1e-12f) ? (SQ2RC * __sinf(k * r) * rinv) : (SQ2RC * k);
    }
    float4* Rb = (float4*)(Rbuf + (size_t)slot * NB_);
    Rb[0] = make_float4(R[0], R[1], R[2], R[3]);
    Rb[1] = make_float4(R[4], R[5], R[6], R[7]);

    float ax = xv[(size_t)idx * 3 + 0];
    float ay = xv[(size_t)idx * 3 + 1];
    float az = xv[(size_t)idx * 3 + 2];
    float dot = ax * ax + ay * ay + az * az;
    float inr = 1.7320508075688772f * rsqrtf(dot + 1e-18f);  // sqrt(3)/|vec|
    rec[slot] = make_float4(ax * inr, ay * inr, az * inr, 0.0f);
    srcb[slot] = src;
}

// ---------- fused gather + prod3body + readout (+ f0 on pass 1) ----------
// one wave per node: 64 lanes = 32 channels x 2 edges/iteration,
// depth-2 src pipeline + depth-1 record pipeline.
template <int PASS>
__global__ void __launch_bounds__(256) k_node(
        const float* __restrict__ Rbuf, const float4* __restrict__ rec,
        const int* __restrict__ srcb, const int* __restrict__ row,
        const float* __restrict__ hin, const float* __restrict__ Wrad,
        const float* __restrict__ Wp, const float* __restrict__ Wr0,
        const float* __restrict__ Wr2, const float* __restrict__ Wm0,
        float* __restrict__ f0out, float* __restrict__ acc) {
    __shared__ float sred[4][6];
    int tid  = threadIdx.x;
    int wv   = tid >> 6;
    int lane = tid & 63;
    int c    = lane & 31;
    int eo   = lane >> 5;
    int gn   = blockIdx.x * 4 + wv;                 // g*N + n
    int g    = gn >> 12;
    int n    = gn & (N_ - 1);

    // per-lane Wrad column in registers
    float wc[NB_][3];
    #pragma unroll
    for (int nb = 0; nb < NB_; ++nb)
        #pragma unroll
        for (int l = 0; l < 3; ++l)
            wc[nb][l] = Wrad[nb * (C_ * 3) + c * 3 + l];

    const int* rp = row + g * (N_ + 1);
    int start = rp[n], end = rp[n + 1];
    const size_t base = (size_t)g * E_;
    const float* hbase = hin + (size_t)g * N_ * C_;

    float A0 = 0, A1x = 0, A1y = 0, A1z = 0;
    float A20 = 0, A21 = 0, A22 = 0, A23 = 0, A24 = 0;

    int s = start + eo;
    // prologue: current record + hs; src one iteration ahead
    float4 RaA, RbA, recA;
    float hsA = 0.f;
    int srcNext = (s + 2 < end) ? srcb[base + s + 2] : 0;
    if (s < end) {
        const float4* Rp = (const float4*)(Rbuf + (base + s) * NB_);
        RaA = Rp[0]; RbA = Rp[1];
        recA = rec[base + s];
        int s0 = srcb[base + s];
        hsA = hbase[(size_t)s0 * C_ + c];
    }

    while (s < end) {
        int sn = s + 2;
        bool more = sn < end;
        float4 RaB, RbB, recB;
        float hsB = 0.f;
        int srcNN = 0;
        if (more) {
            const float4* Rp = (const float4*)(Rbuf + (base + sn) * NB_);
            RaB = Rp[0]; RbB = Rp[1];
            recB = rec[base + sn];
            hsB = hbase[(size_t)srcNext * C_ + c];   // address already resident
            srcNN = (sn + 2 < end) ? srcb[base + sn + 2] : 0;
        }

        // ---- compute current edge ----
        float Rv[NB_] = {RaA.x, RaA.y, RaA.z, RaA.w, RbA.x, RbA.y, RbA.z, RbA.w};
        float w0 = 0.f, w1 = 0.f, w2 = 0.f;
        #pragma unroll
        for (int nb = 0; nb < NB_; ++nb) {
            w0 += Rv[nb] * wc[nb][0];
            w1 += Rv[nb] * wc[nb][1];
            w2 += Rv[nb] * wc[nb][2];
        }
        float m0 = w0 * hsA, m1 = w1 * hsA, m2 = w2 * hsA;
        float vx = recA.x, vy = recA.y, vz = recA.z;   // sqrt(3)*unit vec
        A0  += m0;
        A1x += m1 * vx;
        A1y += m1 * vy;
        A1z += m1 * vz;
        float pxy = vx * vy, pyz = vy * vz, pxz = vx * vz;
        float pxx = vx * vx, pyy = vy * vy, pzz = vz * vz;
        const float CA = 1.2909944487358056f;   // sqrt(15)/3
        const float CB = 0.37267799624996495f;  // sqrt(5)/6
        const float CC = 0.6454972243679028f;   // sqrt(15)/6
        A20 += m2 * (CA * pxy);
        A21 += m2 * (CA * pyz);
        A22 += m2 * (CB * (2.0f * pzz - pxx - pyy));
        A23 += m2 * (CA * pxz);
        A24 += m2 * (CC * (pxx - pyy));

        s = sn;
        RaA = RaB; RbA = RbB; recA = recB; hsA = hsB; srcNext = srcNN;
    }

    // fold the two edge-halves
    A0  += __shfl_xor(A0, 32);
    A1x += __shfl_xor(A1x, 32);
    A1y += __shfl_xor(A1y, 32);
    A1z += __shfl_xor(A1z, 32);
    A20 += __shfl_xor(A20, 32);
    A21 += __shfl_xor(A21, 32);
    A22 += __shfl_xor(A22, 32);
    A23 += __shfl_xor(A23, 32);
    A24 += __shfl_xor(A24, 32);

    // prod3body: B0 and B2 paths (B1 dead w.r.t. outputs)
    float d11 = A1x * A1x + A1y * A1y + A1z * A1z;
    float d22 = A20 * A20 + A21 * A21 + A22 * A22 + A23 * A23 + A24 * A24;
    float B0 = Wp[0 * C_ + c] * A0 * A0 + Wp[1 * C_ + c] * d11 + Wp[2 * C_ + c] * d22;

    float w5 = Wp[5 * C_ + c], w6 = Wp[6 * C_ + c];
    const float S2  = 1.4142135623730951f;
    const float IS6 = 0.4082482904638631f;
    const float IS2 = 0.7071067811865476f;
    float B20 = w5 * A0 * A20 + w6 * (S2 * A1x * A1y);
    float B21 = w5 * A0 * A21 + w6 * (S2 * A1y * A1z);
    float B22 = w5 * A0 * A22 + w6 * ((2.0f * A1z * A1z - A1x * A1x - A1y * A1y) * IS6);
    float B23 = w5 * A0 * A23 + w6 * (S2 * A1x * A1z);
    float B24 = w5 * A0 * A24 + w6 * ((A1x * A1x - A1y * A1y) * IS2);

    float wr0 = Wr0[c], wr2 = Wr2[c];
    float rs  = red32(B0 * wr0);
    float rt0 = red32(B20 * wr2);
    float rt1 = red32(B21 * wr2);
    float rt2 = red32(B22 * wr2);
    float rt3 = red32(B23 * wr2);
    float rt4 = red32(B24 * wr2);
    if (lane == 0) {
        sred[wv][0] = rs;
        sred[wv][1] = rt0; sred[wv][2] = rt1; sred[wv][3] = rt2;
        sred[wv][4] = rt3; sred[wv][5] = rt4;
    }

    if (PASS == 1) {
        float sum = 0.f;
        #pragma unroll
        for (int k = 0; k < C_; ++k) sum += __shfl(B0, k, 32) * Wm0[k * C_ + c];
        float sig = 1.0f / (1.0f + __expf(-sum));
        if (eo == 0) f0out[(size_t)gn * C_ + c] = sum * sig;
    }

    __syncthreads();
    if (tid < 6) {
        float sum = sred[0][tid] + sred[1][tid] + sred[2][tid] + sred[3][tid];
        atomicAdd(&acc[g * 6 + tid], sum);
    }
}

// ---------- finalize ----------
__global__ void k_final(const float* __restrict__ acc, float* __restrict__ out) {
    int g = threadIdx.x;
    if (g >= G_) return;
    float s  = acc[g * 6 + 0];
    float ta = acc[g * 6 + 1], tb = acc[g * 6 + 2], tc = acc[g * 6 + 3],
          td = acc[g * 6 + 4], te = acc[g * 6 + 5];
    const float IS3 = 0.5773502691896258f;
    const float IS6 = 0.4082482904638631f;
    const float IS2 = 0.7071067811865476f;
    float diag = s * IS3;
    float Sxx = -tc * IS6 + te * IS2 + diag;
    float Syy = -tc * IS6 - te * IS2 + diag;
    float Szz = 2.0f * tc * IS6 + diag;
    float Sxy = ta * IS2, Syz = tb * IS2, Sxz = td * IS2;
    float* o = out + g * 9;
    o[0] = Sxx; o[1] = Sxy; o[2] = Sxz;
    o[3] = Sxy; o[4] = Syy; o[5] = Syz;
    o[6] = Sxz; o[7] = Syz; o[8] = Szz;
}

extern "C" void kernel_launch(void* const* d_in, const int* in_sizes, int n_in,
                              void* d_out, int out_size, void* d_ws, size_t ws_size,
                              hipStream_t stream) {
    const float* x     = (const float*)d_in[0];
    const float* xv    = (const float*)d_in[1];
    const float* na    = (const float*)d_in[2];
    const int*   ei    = (const int*)d_in[3];
    const float* Wz    = (const float*)d_in[4];
    const float* Wrad1 = (const float*)d_in[5];
    const float* Wrad2 = (const float*)d_in[6];
    const float* Wp    = (const float*)d_in[7];
    const float* Wr0_1 = (const float*)d_in[8];
    const float* Wr2_1 = (const float*)d_in[9];
    const float* Wm0   = (const float*)d_in[10];
    const float* Wr0_2 = (const float*)d_in[11];
    const float* Wr2_2 = (const float*)d_in[12];
    float* out = (float*)d_out;

    // ---- workspace layout (float units) ----
    float* ws = (float*)d_ws;
    const size_t R_FL   = (size_t)G_ * E_ * NB_;       // 8 MiB
    const size_t REC_FL = (size_t)G_ * E_ * 4;         // 4 MiB
    const size_t H_FL   = (size_t)G_ * N_ * C_;        // 2 MiB
    float*  Rbuf = ws;
    float4* rec  = (float4*)(ws + R_FL);
    float*  h    = ws + R_FL + REC_FL;
    float*  f0   = h + H_FL;
    int*    srcb = (int*)(f0 + H_FL);                  // G*E = 262144 (1 MiB)
    int*    row  = srcb + (size_t)G_ * E_;             // G*(N+1)
    int*    deg  = row + 16392;                        // G*N   (16B-aligned)
    int*    cur  = deg + G_ * N_;                      // G*N
    float*  acc  = (float*)(cur + G_ * N_);            // 24

    hipMemsetAsync(deg, 0, (2 * G_ * N_) * sizeof(int) + 24 * sizeof(float), stream);

    k_h0_hist<<<(G_ * N_ * C_) / 256, 256, 0, stream>>>(na, Wz, h, ei, deg);
    k_scan<<<G_, 1024, 0, stream>>>(deg, row);
    k_prep<<<(G_ * E_) / 256, 256, 0, stream>>>(x, xv, ei, row, cur, Rbuf, rec, srcb);

    k_node<1><<<(G_ * N_) / 4, 256, 0, stream>>>(Rbuf, rec, srcb, row, h,  Wrad1, Wp,
                                                 Wr0_1, Wr2_1, Wm0, f0, acc);
    k_node<2><<<(G_ * N_) / 4, 256, 0, stream>>>(Rbuf, rec, srcb, row, f0, Wrad2, Wp,
                                                 Wr0_2, Wr2_2, nullptr, nullptr, acc);

    k_final<<<1, 64, 0, stream>>>(acc, out);
}